// Round 1
// baseline (534.324 us; speedup 1.0000x reference)
//
#include <hip/hip_runtime.h>
#include <math.h>

// Problem constants: x [B=2, C=32, D=64, H=128, W=128] fp32
constexpr int B  = 2;
constexpr int C  = 32;
constexpr int DD = 64;
constexpr int HH = 128;
constexpr int WW = 128;
constexpr int HW   = HH * WW;        // 16384
constexpr int DHW  = DD * HW;        // 1048576
constexpr int NS   = B * DHW;        // 2097152 spatial sites
constexpr int NS4  = NS / 4;         // one thread handles 4 consecutive w
constexpr int DHW4 = DHW / 4;

// ---------------- Pass 1: channel max + mean pooling ----------------
// Each thread owns 4 consecutive w positions (float4), loops over C=32
// channels. Reads fully coalesced (16 B/lane along W).
__global__ __launch_bounds__(256) void pool_kernel(
    const float* __restrict__ x,
    float* __restrict__ pmax,
    float* __restrict__ pavg) {
  int idx = blockIdx.x * 256 + threadIdx.x;
  if (idx >= NS4) return;
  int b   = idx / DHW4;
  int sp4 = idx - b * DHW4;

  const float4* xp = (const float4*)x + (size_t)b * C * DHW4 + sp4;
  float4 v = xp[0];
  float4 mx = v;
  float4 sm = v;
#pragma unroll 8
  for (int c = 1; c < C; ++c) {
    float4 u = xp[(size_t)c * DHW4];
    mx.x = fmaxf(mx.x, u.x); mx.y = fmaxf(mx.y, u.y);
    mx.z = fmaxf(mx.z, u.z); mx.w = fmaxf(mx.w, u.w);
    sm.x += u.x; sm.y += u.y; sm.z += u.z; sm.w += u.w;
  }
  const float inv = 1.0f / (float)C;
  float4 av = make_float4(sm.x * inv, sm.y * inv, sm.z * inv, sm.w * inv);
  ((float4*)pmax)[(size_t)b * DHW4 + sp4] = mx;
  ((float4*)pavg)[(size_t)b * DHW4 + sp4] = av;
}

// ------- Pass 2: 3x3x3 conv (2->1 ch) + bias + sigmoid + scale x -------
// Each thread computes attn for its 4 w-sites (stencil reads of the tiny
// 16 MiB pooled planes hit L1/L2), then streams all 32 channels of x
// through the sigmoid scale. x read + out write are float4 coalesced.
__global__ __launch_bounds__(256) void attn_scale_kernel(
    const float* __restrict__ x,
    const float* __restrict__ pmax,
    const float* __restrict__ pavg,
    const float* __restrict__ cw,   // [2,3,3,3] (out ch dim = 1)
    const float* __restrict__ cb,   // [1]
    float* __restrict__ out) {
  __shared__ float wsh[54];
  __shared__ float bsh;
  if (threadIdx.x < 54) wsh[threadIdx.x] = cw[threadIdx.x];
  if (threadIdx.x == 0) bsh = cb[0];
  __syncthreads();

  int idx = blockIdx.x * 256 + threadIdx.x;
  if (idx >= NS4) return;
  int b   = idx / DHW4;
  int sp4 = idx - b * DHW4;
  int sp  = sp4 * 4;
  int d   = sp / HW;
  int r   = sp - d * HW;
  int h   = r / WW;
  int w0  = r - h * WW;

  float acc0 = bsh, acc1 = bsh, acc2 = bsh, acc3 = bsh;

#pragma unroll
  for (int ch = 0; ch < 2; ++ch) {
    const float* p  = (ch == 0 ? pmax : pavg) + (size_t)b * DHW;
    const float* wt = wsh + ch * 27;
#pragma unroll
    for (int dd = -1; dd <= 1; ++dd) {
      int zd = d + dd;
      if (zd < 0 || zd >= DD) continue;   // zero padding
#pragma unroll
      for (int hh = -1; hh <= 1; ++hh) {
        int zh = h + hh;
        if (zh < 0 || zh >= HH) continue; // zero padding
        const float* row = p + zd * HW + zh * WW;
        const float* wr  = wt + (dd + 1) * 9 + (hh + 1) * 3;
        float v[6];
#pragma unroll
        for (int j = 0; j < 6; ++j) {
          int wj = w0 - 1 + j;
          v[j] = (wj >= 0 && wj < WW) ? row[wj] : 0.0f;
        }
#pragma unroll
        for (int t = 0; t < 3; ++t) {
          float wv = wr[t];
          acc0 = fmaf(wv, v[t],     acc0);
          acc1 = fmaf(wv, v[t + 1], acc1);
          acc2 = fmaf(wv, v[t + 2], acc2);
          acc3 = fmaf(wv, v[t + 3], acc3);
        }
      }
    }
  }

  float4 sig;
  sig.x = 1.0f / (1.0f + __expf(-acc0));
  sig.y = 1.0f / (1.0f + __expf(-acc1));
  sig.z = 1.0f / (1.0f + __expf(-acc2));
  sig.w = 1.0f / (1.0f + __expf(-acc3));

  const float4* xp = (const float4*)x   + (size_t)b * C * DHW4 + sp4;
  float4*       op = (float4*)out       + (size_t)b * C * DHW4 + sp4;
#pragma unroll 4
  for (int c = 0; c < C; ++c) {
    float4 v = xp[(size_t)c * DHW4];
    v.x *= sig.x; v.y *= sig.y; v.z *= sig.z; v.w *= sig.w;
    op[(size_t)c * DHW4] = v;
  }
}

extern "C" void kernel_launch(void* const* d_in, const int* in_sizes, int n_in,
                              void* d_out, int out_size, void* d_ws, size_t ws_size,
                              hipStream_t stream) {
  const float* x  = (const float*)d_in[0];
  const float* cw = (const float*)d_in[1];
  const float* cb = (const float*)d_in[2];
  float* out  = (float*)d_out;
  float* pmax = (float*)d_ws;          // NS floats (8 MiB)
  float* pavg = pmax + NS;             // NS floats (8 MiB)

  dim3 blk(256);
  dim3 grid((NS4 + 255) / 256);        // 2048 blocks
  pool_kernel<<<grid, blk, 0, stream>>>(x, pmax, pavg);
  attn_scale_kernel<<<grid, blk, 0, stream>>>(x, pmax, pavg, cw, cb, out);
}